// Round 1
// baseline (547.925 us; speedup 1.0000x reference)
//
#include <hip/hip_runtime.h>
#include <cfloat>

#define N_TOK   32768
#define DIM     64
#define K_CODES 8192
#define TB      64              // tokens per block
#define CB      64              // codes per LDS chunk
#define NCHUNK  (K_CODES / CB)

#define IDX_OFF  (N_TOK * DIM)
#define LOSS_OFF (N_TOK * DIM + N_TOK)
#define WS_ESQ   0
#define WS_PART  K_CODES

// ---------------------------------------------------------------------------
// e_sq[k] = numpy-pairwise sum of squares of embedding row k (bitwise np order)
// 8 lanes per code: lane q accumulates x[q]^2 + x[q+8]^2 + ... sequentially,
// then ((r0+r1)+(r2+r3))+((r4+r5)+(r6+r7)) via xor-shuffles (add is commutative,
// so per-pair order matches numpy exactly).
// ---------------------------------------------------------------------------
__global__ __launch_bounds__(256) void esq_kernel(const float* __restrict__ emb,
                                                  float* __restrict__ esq) {
#pragma clang fp contract(off)
    const int tid = threadIdx.x;
    const int q = tid & 7;
    const int code = blockIdx.x * 32 + (tid >> 3);
    const float* row = emb + code * DIM;
    float x = row[q];
    float r = x * x;
#pragma unroll
    for (int m = 1; m < 8; ++m) {
        float y = row[q + 8 * m];
        float sq = y * y;
        r = r + sq;
    }
    r = r + __shfl_xor(r, 1, 64);   // (r0+r1) level
    r = r + __shfl_xor(r, 2, 64);   // ((r0+r1)+(r2+r3)) level
    r = r + __shfl_xor(r, 4, 64);   // + ((r4+r5)+(r6+r7))
    if (q == 0) esq[code] = r;
}

// ---------------------------------------------------------------------------
// Main scan: block = 64 tokens, loops over 128 chunks of 64 codes.
// Thread (tx,ty) computes 4 tokens x 4 codes; d replicates numpy f32 rounding.
// ---------------------------------------------------------------------------
__global__ __launch_bounds__(256) void vq_main(const float* __restrict__ hid,
                                               const float* __restrict__ emb,
                                               const float* __restrict__ esq,
                                               float* __restrict__ out_zq,
                                               float* __restrict__ out_idx,
                                               float* __restrict__ partials) {
#pragma clang fp contract(off)
    __shared__ float zT[DIM][TB];     // zT[j][t]
    __shared__ float eT[DIM][CB];     // eT[j][c]
    __shared__ float zsq_s[TB];
    __shared__ float lred[4];

    const int tid = threadIdx.x;
    const int bid = blockIdx.x;
    const int tb = bid * TB;

    // ---- stage z tile, transposed ----
    {
        const int t = tid >> 2;         // 0..63
        const int jc0 = tid & 3;
        const float4* h4 = reinterpret_cast<const float4*>(hid + (tb + t) * DIM);
        float4 v[4];
#pragma unroll
        for (int i = 0; i < 4; ++i) v[i] = h4[jc0 + 4 * i];
#pragma unroll
        for (int i = 0; i < 4; ++i) {
            const int j = (jc0 + 4 * i) * 4;
            zT[j + 0][t] = v[i].x;
            zT[j + 1][t] = v[i].y;
            zT[j + 2][t] = v[i].z;
            zT[j + 3][t] = v[i].w;
        }
    }
    __syncthreads();

    // ---- z_sq per token, numpy pairwise order (threads 0..63) ----
    if (tid < TB) {
        const int t = tid;
        float r[8];
#pragma unroll
        for (int q = 0; q < 8; ++q) {
            float x = zT[q][t];
            r[q] = x * x;
#pragma unroll
            for (int m = 1; m < 8; ++m) {
                float y = zT[q + 8 * m][t];
                float sq = y * y;
                r[q] = r[q] + sq;
            }
        }
        const float s01 = r[0] + r[1], s23 = r[2] + r[3];
        const float s45 = r[4] + r[5], s67 = r[6] + r[7];
        zsq_s[t] = (s01 + s23) + (s45 + s67);
    }

    const int tx = tid & 15;        // code group
    const int ty = tid >> 4;        // token group
    const int cg = tx * 4;
    const int tg = ty * 4;

    // prefetch chunk 0 into registers (global->reg->LDS pipeline)
    const int pc  = tid >> 2;       // code 0..63 within chunk
    const int pj0 = tid & 3;
    float4 pref[4];
    {
        const float4* e4 = reinterpret_cast<const float4*>(emb + pc * DIM);
#pragma unroll
        for (int i = 0; i < 4; ++i) pref[i] = e4[pj0 + 4 * i];
    }
    __syncthreads();                // zsq_s ready

    float zsq_r[4];
#pragma unroll
    for (int a = 0; a < 4; ++a) zsq_r[a] = zsq_s[tg + a];

    float best[4] = {FLT_MAX, FLT_MAX, FLT_MAX, FLT_MAX};
    int   bidx[4] = {0, 0, 0, 0};

    for (int ch = 0; ch < NCHUNK; ++ch) {
        // write prefetched chunk to LDS (transposed)
#pragma unroll
        for (int i = 0; i < 4; ++i) {
            const int j = (pj0 + 4 * i) * 4;
            eT[j + 0][pc] = pref[i].x;
            eT[j + 1][pc] = pref[i].y;
            eT[j + 2][pc] = pref[i].z;
            eT[j + 3][pc] = pref[i].w;
        }
        __syncthreads();

        // prefetch next chunk (latency hides under compute below)
        if (ch + 1 < NCHUNK) {
            const float4* e4 =
                reinterpret_cast<const float4*>(emb + ((ch + 1) * CB + pc) * DIM);
#pragma unroll
            for (int i = 0; i < 4; ++i) pref[i] = e4[pj0 + 4 * i];
        }

        const int kb = ch * CB;
        const float4 es = *reinterpret_cast<const float4*>(esq + kb + cg);

        float acc[4][4];
#pragma unroll
        for (int a = 0; a < 4; ++a)
#pragma unroll
            for (int b = 0; b < 4; ++b) acc[a][b] = 0.f;

        // sequential-j FMA chains: bitwise-matches BLAS k-sequential accumulation
#pragma unroll 16
        for (int j = 0; j < DIM; ++j) {
            const float4 zv = *reinterpret_cast<const float4*>(&zT[j][tg]);
            const float4 ev = *reinterpret_cast<const float4*>(&eT[j][cg]);
            const float za[4] = {zv.x, zv.y, zv.z, zv.w};
            const float eb[4] = {ev.x, ev.y, ev.z, ev.w};
#pragma unroll
            for (int a = 0; a < 4; ++a)
#pragma unroll
                for (int b = 0; b < 4; ++b)
                    acc[a][b] = fmaf(za[a], eb[b], acc[a][b]);
        }

        // d = fl( fl(z_sq + e_sq) - 2*dot ); strict < keeps earliest index
        const float esv[4] = {es.x, es.y, es.z, es.w};
#pragma unroll
        for (int b = 0; b < 4; ++b) {
            const int k = kb + cg + b;
#pragma unroll
            for (int a = 0; a < 4; ++a) {
                const float s = zsq_r[a] + esv[b];
                const float d = fmaf(-2.0f, acc[a][b], s);
                if (d < best[a]) { best[a] = d; bidx[a] = k; }
            }
        }
        __syncthreads();
    }

    // ---- combine across the 16 lanes sharing a token group (first-index ties) ----
#pragma unroll
    for (int off = 1; off < 16; off <<= 1) {
#pragma unroll
        for (int a = 0; a < 4; ++a) {
            const float ov = __shfl_xor(best[a], off, 64);
            const int   oi = __shfl_xor(bidx[a], off, 64);
            if (ov < best[a] || (ov == best[a] && oi < bidx[a])) {
                best[a] = ov; bidx[a] = oi;
            }
        }
    }

    // ---- outputs: indices, z_q = h + (q - h), loss partial ----
    float lsum = 0.f;
#pragma unroll
    for (int a = 0; a < 4; ++a) {
        const int t = tb + tg + a;
        const int k = bidx[a];
        if (tx == 0) out_idx[t] = (float)k;
        const float4 q4 = reinterpret_cast<const float4*>(emb + k * DIM)[tx];
        const float4 h4 = reinterpret_cast<const float4*>(hid + t * DIM)[tx];
        float4 zq;
        float dx;
        dx = q4.x - h4.x; zq.x = h4.x + dx; lsum += dx * dx;
        dx = q4.y - h4.y; zq.y = h4.y + dx; lsum += dx * dx;
        dx = q4.z - h4.z; zq.z = h4.z + dx; lsum += dx * dx;
        dx = q4.w - h4.w; zq.w = h4.w + dx; lsum += dx * dx;
        reinterpret_cast<float4*>(out_zq + t * DIM)[tx] = zq;
    }

    // deterministic block reduction of loss partial
#pragma unroll
    for (int off = 32; off >= 1; off >>= 1) lsum += __shfl_xor(lsum, off, 64);
    const int wid = tid >> 6;
    if ((tid & 63) == 0) lred[wid] = lsum;
    __syncthreads();
    if (tid == 0) partials[bid] = (lred[0] + lred[1]) + (lred[2] + lred[3]);
}

// ---------------------------------------------------------------------------
// Final loss: deterministic tree-reduce of 512 block partials
// ---------------------------------------------------------------------------
__global__ __launch_bounds__(256) void loss_kernel(const float* __restrict__ partials,
                                                   float* __restrict__ out_loss) {
#pragma clang fp contract(off)
    __shared__ float s[256];
    const int t = threadIdx.x;
    s[t] = partials[t] + partials[t + 256];
    __syncthreads();
    for (int off = 128; off >= 1; off >>= 1) {
        if (t < off) s[t] = s[t] + s[t + off];
        __syncthreads();
    }
    if (t == 0) {
        const float m = s[0] * (1.0f / 2097152.0f);  // exact: /2^21
        out_loss[0] = m + 0.25f * m;
    }
}

extern "C" void kernel_launch(void* const* d_in, const int* in_sizes, int n_in,
                              void* d_out, int out_size, void* d_ws, size_t ws_size,
                              hipStream_t stream) {
    const float* hid = (const float*)d_in[0];
    const float* emb = (const float*)d_in[1];
    float* out = (float*)d_out;
    float* ws = (float*)d_ws;
    float* esq = ws + WS_ESQ;
    float* partials = ws + WS_PART;

    esq_kernel<<<K_CODES / 32, 256, 0, stream>>>(emb, esq);
    vq_main<<<N_TOK / TB, 256, 0, stream>>>(hid, emb, esq,
                                            out, out + IDX_OFF, partials);
    loss_kernel<<<1, 256, 0, stream>>>(partials, out + LOSS_OFF);
}

// Round 2
// 538.346 us; speedup vs baseline: 1.0178x; 1.0178x over previous
//
#include <hip/hip_runtime.h>
#include <cfloat>

#define N_TOK   32768
#define DIM     64
#define K_CODES 8192
#define TB      128             // tokens per block
#define CB      128             // codes per LDS chunk
#define NCHUNK  (K_CODES / CB)
#define LS      132             // LDS row stride in floats (pad: 2-way banks, 16B aligned)

#define IDX_OFF  (N_TOK * DIM)
#define LOSS_OFF (N_TOK * DIM + N_TOK)
#define WS_ESQ   0
#define WS_PART  K_CODES

// ---------------------------------------------------------------------------
// e_sq[k] = numpy-pairwise sum of squares of embedding row k (bitwise np order)
// ---------------------------------------------------------------------------
__global__ __launch_bounds__(256) void esq_kernel(const float* __restrict__ emb,
                                                  float* __restrict__ esq) {
#pragma clang fp contract(off)
    const int tid = threadIdx.x;
    const int q = tid & 7;
    const int code = blockIdx.x * 32 + (tid >> 3);
    const float* row = emb + code * DIM;
    float x = row[q];
    float r = x * x;
#pragma unroll
    for (int m = 1; m < 8; ++m) {
        float y = row[q + 8 * m];
        float sq = y * y;
        r = r + sq;
    }
    r = r + __shfl_xor(r, 1, 64);
    r = r + __shfl_xor(r, 2, 64);
    r = r + __shfl_xor(r, 4, 64);
    if (q == 0) esq[code] = r;
}

// ---------------------------------------------------------------------------
// Main scan: block = 128 tokens; 64 chunks of 128 codes.
// 16tx x 16ty threads, each computes 8 tokens x 8 codes.
// Thread's codes: {4tx..4tx+3} U {64+4tx..64+4tx+3}  (ascending -> tie-break ok)
// ---------------------------------------------------------------------------
__global__ __launch_bounds__(256, 1) void vq_main(const float* __restrict__ hid,
                                                  const float* __restrict__ emb,
                                                  const float* __restrict__ esq,
                                                  float* __restrict__ out_zq,
                                                  float* __restrict__ out_idx,
                                                  float* __restrict__ partials) {
#pragma clang fp contract(off)
    __shared__ float zT[DIM][LS];     // zT[j][t], t in [0,128)
    __shared__ float eT[DIM][LS];     // eT[j][c], c in [0,128)
    __shared__ float zsq_s[TB];
    __shared__ float lred[4];

    const int tid = threadIdx.x;
    const int bid = blockIdx.x;
    const int tb = bid * TB;

    // ---- stage z tile, transposed (32 floats per thread) ----
    {
        const int tr = tid >> 1;            // token row 0..127
        const int tj0 = (tid & 1) * 32;     // j-range start
        const float4* h4 = reinterpret_cast<const float4*>(hid + (tb + tr) * DIM + tj0);
        float4 v[8];
#pragma unroll
        for (int i = 0; i < 8; ++i) v[i] = h4[i];
#pragma unroll
        for (int i = 0; i < 8; ++i) {
            const int j = tj0 + 4 * i;
            zT[j + 0][tr] = v[i].x;
            zT[j + 1][tr] = v[i].y;
            zT[j + 2][tr] = v[i].z;
            zT[j + 3][tr] = v[i].w;
        }
    }
    __syncthreads();

    // ---- z_sq per token, numpy pairwise order (threads 0..127) ----
    if (tid < TB) {
        const int t = tid;
        float r[8];
#pragma unroll
        for (int q = 0; q < 8; ++q) {
            float x = zT[q][t];
            r[q] = x * x;
#pragma unroll
            for (int m = 1; m < 8; ++m) {
                float y = zT[q + 8 * m][t];
                float sq = y * y;
                r[q] = r[q] + sq;
            }
        }
        const float s01 = r[0] + r[1], s23 = r[2] + r[3];
        const float s45 = r[4] + r[5], s67 = r[6] + r[7];
        zsq_s[t] = (s01 + s23) + (s45 + s67);
    }

    const int tx = tid & 15;        // code lane
    const int ty = tid >> 4;        // token group
    const int tg = ty * 8;          // 8 tokens per thread
    const int cg = tx * 4;          // first code quad; second at cg+64

    // prefetch chunk 0 into registers (global->reg->LDS pipeline)
    const int pc  = tid >> 1;            // code row 0..127 within chunk
    const int pj0 = (tid & 1) * 32;
    float4 pref[8];
    {
        const float4* e4 = reinterpret_cast<const float4*>(emb + pc * DIM + pj0);
#pragma unroll
        for (int i = 0; i < 8; ++i) pref[i] = e4[i];
    }
    __syncthreads();                // zsq_s ready

    float zsq_r[8];
#pragma unroll
    for (int a = 0; a < 8; ++a) zsq_r[a] = zsq_s[tg + a];

    float best[8];
    int   bidx[8];
#pragma unroll
    for (int a = 0; a < 8; ++a) { best[a] = FLT_MAX; bidx[a] = 0; }

    for (int ch = 0; ch < NCHUNK; ++ch) {
        // write prefetched chunk to LDS (transposed)
#pragma unroll
        for (int i = 0; i < 8; ++i) {
            const int j = pj0 + 4 * i;
            eT[j + 0][pc] = pref[i].x;
            eT[j + 1][pc] = pref[i].y;
            eT[j + 2][pc] = pref[i].z;
            eT[j + 3][pc] = pref[i].w;
        }
        __syncthreads();

        // prefetch next chunk (hides under compute below)
        if (ch + 1 < NCHUNK) {
            const float4* e4 =
                reinterpret_cast<const float4*>(emb + ((ch + 1) * CB + pc) * DIM + pj0);
#pragma unroll
            for (int i = 0; i < 8; ++i) pref[i] = e4[i];
        }

        const int kb = ch * CB;
        const float4 es0 = *reinterpret_cast<const float4*>(esq + kb + cg);
        const float4 es1 = *reinterpret_cast<const float4*>(esq + kb + 64 + cg);

        float acc[8][8];
#pragma unroll
        for (int a = 0; a < 8; ++a)
#pragma unroll
            for (int b = 0; b < 8; ++b) acc[a][b] = 0.f;

        // sequential-j FMA chains: bitwise-matches BLAS k-sequential accumulation
#pragma unroll 8
        for (int j = 0; j < DIM; ++j) {
            const float4 zv0 = *reinterpret_cast<const float4*>(&zT[j][tg]);
            const float4 zv1 = *reinterpret_cast<const float4*>(&zT[j][tg + 4]);
            const float4 ev0 = *reinterpret_cast<const float4*>(&eT[j][cg]);
            const float4 ev1 = *reinterpret_cast<const float4*>(&eT[j][cg + 64]);
            const float za[8] = {zv0.x, zv0.y, zv0.z, zv0.w, zv1.x, zv1.y, zv1.z, zv1.w};
            const float eb[8] = {ev0.x, ev0.y, ev0.z, ev0.w, ev1.x, ev1.y, ev1.z, ev1.w};
#pragma unroll
            for (int a = 0; a < 8; ++a)
#pragma unroll
                for (int b = 0; b < 8; ++b)
                    acc[a][b] = fmaf(za[a], eb[b], acc[a][b]);
        }

        // d = fl( fl(z_sq + e_sq) - 2*dot ); strict < keeps earliest index
        const float esv[8] = {es0.x, es0.y, es0.z, es0.w, es1.x, es1.y, es1.z, es1.w};
#pragma unroll
        for (int b = 0; b < 8; ++b) {
            const int k = kb + ((b < 4) ? (cg + b) : (64 + cg + (b - 4)));
#pragma unroll
            for (int a = 0; a < 8; ++a) {
                const float s = zsq_r[a] + esv[b];
                const float d = fmaf(-2.0f, acc[a][b], s);
                if (d < best[a]) { best[a] = d; bidx[a] = k; }
            }
        }
        __syncthreads();
    }

    // ---- combine across the 16 lanes sharing a token group (first-index ties) ----
#pragma unroll
    for (int off = 1; off < 16; off <<= 1) {
#pragma unroll
        for (int a = 0; a < 8; ++a) {
            const float ov = __shfl_xor(best[a], off, 64);
            const int   oi = __shfl_xor(bidx[a], off, 64);
            if (ov < best[a] || (ov == best[a] && oi < bidx[a])) {
                best[a] = ov; bidx[a] = oi;
            }
        }
    }

    // ---- outputs: indices, z_q = h + (q - h), loss partial ----
    float lsum = 0.f;
#pragma unroll
    for (int a = 0; a < 8; ++a) {
        const int t = tb + tg + a;
        const int k = bidx[a];
        if (tx == 0) out_idx[t] = (float)k;
        const float4 q4 = reinterpret_cast<const float4*>(emb + k * DIM)[tx];
        const float4 h4 = reinterpret_cast<const float4*>(hid + t * DIM)[tx];
        float4 zq;
        float dx;
        dx = q4.x - h4.x; zq.x = h4.x + dx; lsum += dx * dx;
        dx = q4.y - h4.y; zq.y = h4.y + dx; lsum += dx * dx;
        dx = q4.z - h4.z; zq.z = h4.z + dx; lsum += dx * dx;
        dx = q4.w - h4.w; zq.w = h4.w + dx; lsum += dx * dx;
        reinterpret_cast<float4*>(out_zq + t * DIM)[tx] = zq;
    }

    // deterministic block reduction of loss partial
#pragma unroll
    for (int off = 32; off >= 1; off >>= 1) lsum += __shfl_xor(lsum, off, 64);
    const int wid = tid >> 6;
    if ((tid & 63) == 0) lred[wid] = lsum;
    __syncthreads();
    if (tid == 0) partials[bid] = (lred[0] + lred[1]) + (lred[2] + lred[3]);
}

// ---------------------------------------------------------------------------
// Final loss: deterministic tree-reduce of 256 block partials
// ---------------------------------------------------------------------------
__global__ __launch_bounds__(256) void loss_kernel(const float* __restrict__ partials,
                                                   float* __restrict__ out_loss) {
#pragma clang fp contract(off)
    __shared__ float s[256];
    const int t = threadIdx.x;
    s[t] = partials[t];
    __syncthreads();
    for (int off = 128; off >= 1; off >>= 1) {
        if (t < off) s[t] = s[t] + s[t + off];
        __syncthreads();
    }
    if (t == 0) {
        const float m = s[0] * (1.0f / 2097152.0f);  // exact: /2^21
        out_loss[0] = m + 0.25f * m;
    }
}

extern "C" void kernel_launch(void* const* d_in, const int* in_sizes, int n_in,
                              void* d_out, int out_size, void* d_ws, size_t ws_size,
                              hipStream_t stream) {
    const float* hid = (const float*)d_in[0];
    const float* emb = (const float*)d_in[1];
    float* out = (float*)d_out;
    float* ws = (float*)d_ws;
    float* esq = ws + WS_ESQ;
    float* partials = ws + WS_PART;

    esq_kernel<<<K_CODES / 32, 256, 0, stream>>>(emb, esq);
    vq_main<<<N_TOK / TB, 256, 0, stream>>>(hid, emb, esq,
                                            out, out + IDX_OFF, partials);
    loss_kernel<<<1, 256, 0, stream>>>(partials, out + LOSS_OFF);
}